// Round 4
// baseline (143.982 us; speedup 1.0000x reference)
//
#include <hip/hip_runtime.h>
#include <math.h>
#include <stdint.h>

#define N 4096
#define D 512
#define C 128
#define ALPHA 0.0005f
#define NT_TILES 32                 // N/128
#define TRI (NT_TILES * (NT_TILES + 1) / 2)   // 528 count tiles
#define NBLK (TRI + N / 128)                  // + 32 CE tiles = 560

typedef __bf16 bf16x8 __attribute__((ext_vector_type(8)));
typedef float f32x4 __attribute__((ext_vector_type(4)));

// async global->LDS, 16B per lane. LDS dest must be wave-uniform base + lane*16.
__device__ __forceinline__ void async16(const void* g, void* l) {
    __builtin_amdgcn_global_load_lds(
        reinterpret_cast<const __attribute__((address_space(1))) uint32_t*>(
            reinterpret_cast<uintptr_t>(g)),
        reinterpret_cast<__attribute__((address_space(3))) uint32_t*>(
            reinterpret_cast<uintptr_t>(l)),
        16, 0, 0);
}

// ---------------------------------------------------------------------------
// prep: blocks [0,N)    : sq[i]=||x_i||^2 ; dot0[i]=x_i.x_0 ; xb=bf16(x); cnt[i]=0
//       blocks [N,N+256): Wtb[n][k] = bf16(W[k][n]) ; block N also zeroes done
// ---------------------------------------------------------------------------
__global__ __launch_bounds__(256) void prep_kernel(const float* __restrict__ x,
                                                   float* __restrict__ sq,
                                                   float* __restrict__ dot0,
                                                   __bf16* __restrict__ xb,
                                                   const float* __restrict__ W,
                                                   __bf16* __restrict__ Wtb,
                                                   unsigned* __restrict__ cnt,
                                                   unsigned* __restrict__ done) {
    if (blockIdx.x >= N) {
        const int tid = (blockIdx.x - N) * 256 + threadIdx.x;  // 0..D*C-1
        const int k = tid >> 7;
        const int n = tid & 127;
        Wtb[(size_t)n * D + k] = (__bf16)W[tid];
        if (blockIdx.x == N && threadIdx.x == 0) *done = 0u;
        return;
    }
    const int i = blockIdx.x;
    const int t = threadIdx.x;
    if (t == 0) cnt[i] = 0u;
    float s1 = 0.f, s2 = 0.f;
    for (int k = t; k < D; k += 256) {
        float v = x[(size_t)i * D + k];
        xb[(size_t)i * D + k] = (__bf16)v;
        s1 += v * v;
        s2 += v * x[k];           // x[0,k]
    }
    for (int o = 32; o; o >>= 1) {
        s1 += __shfl_down(s1, o);
        s2 += __shfl_down(s2, o);
    }
    __shared__ float r1[4], r2[4];
    if ((t & 63) == 0) { r1[t >> 6] = s1; r2[t >> 6] = s2; }
    __syncthreads();
    if (t == 0) {
        sq[i]   = r1[0] + r1[1] + r1[2] + r1[3];
        dot0[i] = r2[0] + r2[1] + r2[2] + r2[3];
    }
}

// ---------------------------------------------------------------------------
// fused_mfma:
//   blocks [0,TRI)      : neighbor-count tile (ti,tj), tj>=ti, symmetric update
//   blocks [TRI,TRI+32) : CE tile (128 rows x 128 logits + log-softmax)
//   last block to finish: grid-wide finalize (mean loss + ALPHA*reg) -> out
// 128x128 tile, BK=64, 4 waves 2x2, 4x4 frags of mfma_f32_16x16x32_bf16.
// LDS slot XOR-swizzle (source-side) keeps global loads coalesced AND frag
// ds_read_b128 conflict-free.
// ---------------------------------------------------------------------------
__global__ __launch_bounds__(256) void fused_mfma(const __bf16* __restrict__ xb,
                                                  const __bf16* __restrict__ Wtb,
                                                  const float* __restrict__ sq,
                                                  const float* __restrict__ dot0,
                                                  const int* __restrict__ y,
                                                  const float* __restrict__ b,
                                                  unsigned* __restrict__ cnt,
                                                  float* __restrict__ lossrow,
                                                  const float* __restrict__ Y,
                                                  unsigned* __restrict__ done,
                                                  float* __restrict__ out) {
    __shared__ __bf16 Alds[128 * 64];
    __shared__ __bf16 Blds[128 * 64];
    __shared__ float rmax[128][2];
    __shared__ float rsum[128][2];
    const int t = threadIdx.x;
    const int w = t >> 6, l = t & 63;
    const int wy = w >> 1, wx = w & 1;
    const int kg = l >> 4, lr = l & 15;

    const int bid = (int)blockIdx.x;
    const bool isCE = (bid >= TRI);
    int bi, bj;
    bool diag = false;
    const __bf16* Bbase;
    if (isCE) {
        bi = (bid - TRI) * 128;
        bj = 0;
        Bbase = Wtb;
    } else {
        int tj = (int)((sqrtf(8.f * (float)bid + 1.f) - 1.f) * 0.5f);
        while (tj * (tj + 1) / 2 > bid) --tj;
        while ((tj + 1) * (tj + 2) / 2 <= bid) ++tj;
        const int ti = bid - tj * (tj + 1) / 2;
        bi = ti * 128;
        bj = tj * 128;
        diag = (ti == tj);
        Bbase = xb + (size_t)bj * D;
    }
    const __bf16* Abase = xb + (size_t)bi * D;

    f32x4 acc[4][4];
    const f32x4 zero = {0.f, 0.f, 0.f, 0.f};
#pragma unroll
    for (int mt = 0; mt < 4; ++mt)
#pragma unroll
        for (int nt = 0; nt < 4; ++nt) acc[mt][nt] = zero;

    for (int kc = 0; kc < D; kc += 64) {
        __syncthreads();
#pragma unroll
        for (int s = 0; s < 4; ++s) {
            const int e = t + 256 * s;          // 0..1023
            const int r = e >> 3;               // tile row 0..127
            const int c = e & 7;                // LDS slot (8 bf16 = 16 B)
            const int sc = c ^ (r & 7);         // swizzled source col-group
            async16(Abase + (size_t)r * D + kc + sc * 8, (char*)Alds + e * 16);
            if (!diag)
                async16(Bbase + (size_t)r * D + kc + sc * 8, (char*)Blds + e * 16);
        }
        __syncthreads();
        const __bf16* Bl = diag ? Alds : Blds;
#pragma unroll
        for (int kk = 0; kk < 2; ++kk) {
            bf16x8 av[4], bv[4];
#pragma unroll
            for (int mt = 0; mt < 4; ++mt) {
                const int row = wy * 64 + mt * 16 + lr;
                const int slot = (kk * 4 + kg) ^ (row & 7);
                av[mt] = *(const bf16x8*)(Alds + row * 64 + slot * 8);
            }
#pragma unroll
            for (int nt = 0; nt < 4; ++nt) {
                const int row = wx * 64 + nt * 16 + lr;
                const int slot = (kk * 4 + kg) ^ (row & 7);
                bv[nt] = *(const bf16x8*)(Bl + row * 64 + slot * 8);
            }
#pragma unroll
            for (int mt = 0; mt < 4; ++mt)
#pragma unroll
                for (int nt = 0; nt < 4; ++nt)
                    acc[mt][nt] = __builtin_amdgcn_mfma_f32_16x16x32_bf16(av[mt], bv[nt], acc[mt][nt], 0, 0, 0);
        }
    }

    if (isCE) {
        // ---- CE epilogue: log-softmax over 128 cols, pick col y[i] ----
        int jn[4]; float bb[4];
#pragma unroll
        for (int nt = 0; nt < 4; ++nt) { jn[nt] = wx * 64 + nt * 16 + lr; bb[nt] = b[jn[nt]]; }
#pragma unroll
        for (int mt = 0; mt < 4; ++mt)
#pragma unroll
            for (int r = 0; r < 4; ++r) {
                float m = acc[mt][0][r] + bb[0];
#pragma unroll
                for (int nt = 1; nt < 4; ++nt) m = fmaxf(m, acc[mt][nt][r] + bb[nt]);
                m = fmaxf(m, __shfl_xor(m, 1));
                m = fmaxf(m, __shfl_xor(m, 2));
                m = fmaxf(m, __shfl_xor(m, 4));
                m = fmaxf(m, __shfl_xor(m, 8));
                if (lr == 0) rmax[wy * 64 + mt * 16 + kg * 4 + r][wx] = m;
            }
        __syncthreads();
        float mrow[4][4];
#pragma unroll
        for (int mt = 0; mt < 4; ++mt)
#pragma unroll
            for (int r = 0; r < 4; ++r) {
                const int ri = wy * 64 + mt * 16 + kg * 4 + r;
                mrow[mt][r] = fmaxf(rmax[ri][0], rmax[ri][1]);
                float s = 0.f;
#pragma unroll
                for (int nt = 0; nt < 4; ++nt) s += expf(acc[mt][nt][r] + bb[nt] - mrow[mt][r]);
                s += __shfl_xor(s, 1);
                s += __shfl_xor(s, 2);
                s += __shfl_xor(s, 4);
                s += __shfl_xor(s, 8);
                if (lr == 0) rsum[ri][wx] = s;
            }
        __syncthreads();
#pragma unroll
        for (int mt = 0; mt < 4; ++mt)
#pragma unroll
            for (int r = 0; r < 4; ++r) {
                const int ri = wy * 64 + mt * 16 + kg * 4 + r;
                const int i = bi + ri;
                const float s = rsum[ri][0] + rsum[ri][1];
                const int yi = y[i];
#pragma unroll
                for (int nt = 0; nt < 4; ++nt)
                    if (jn[nt] == yi)
                        lossrow[i] = -(acc[mt][nt][r] + bb[nt] - mrow[mt][r] - logf(s));
            }
    } else {
        // ---- count epilogue (symmetric) ----
        const float sq0 = sq[0];
        int jn[4]; float sqj[4], thrj[4];
#pragma unroll
        for (int nt = 0; nt < 4; ++nt) {
            jn[nt] = bj + wx * 64 + nt * 16 + lr;
            sqj[nt] = sq[jn[nt]];
            thrj[nt] = sq0 - 2.0f * dot0[jn[nt]];
        }
        unsigned cj[4] = {0u, 0u, 0u, 0u};
#pragma unroll
        for (int mt = 0; mt < 4; ++mt)
#pragma unroll
            for (int r = 0; r < 4; ++r) {
                const int i = bi + wy * 64 + mt * 16 + kg * 4 + r;
                const float thri = sq0 - 2.0f * dot0[i];
                const float sqi = sq[i];
                unsigned ci = 0;
                if (diag) {
#pragma unroll
                    for (int nt = 0; nt < 4; ++nt) {
                        const float d = acc[mt][nt][r];
                        const int j = jn[nt];
                        if (sqj[nt] - 2.0f * d < thri && j != i && j != 0) ++ci;
                    }
                } else {
                    // bj > bi: j >= 128 > 0 and i < bj <= j, no guards needed
#pragma unroll
                    for (int nt = 0; nt < 4; ++nt) {
                        const float d = acc[mt][nt][r];
                        if (sqj[nt] - 2.0f * d < thri) ++ci;
                        if (sqi - 2.0f * d < thrj[nt] && i != 0) ++cj[nt];
                    }
                }
                ci += __shfl_xor((int)ci, 1);
                ci += __shfl_xor((int)ci, 2);
                ci += __shfl_xor((int)ci, 4);
                ci += __shfl_xor((int)ci, 8);
                if (lr == 0 && ci) atomicAdd(&cnt[i], ci);
            }
        if (!diag) {
#pragma unroll
            for (int nt = 0; nt < 4; ++nt) {
                unsigned v = cj[nt];
                v += __shfl_xor((int)v, 16);
                v += __shfl_xor((int)v, 32);
                if (l < 16 && v) atomicAdd(&cnt[jn[nt]], v);
            }
        }
    }

    // ---- last-block finalize ----
    __threadfence();                       // release: lossrow stores + cnt atomics visible
    __shared__ unsigned lastFlag;
    if (t == 0) lastFlag = (atomicAdd(done, 1u) == (unsigned)(NBLK - 1)) ? 1u : 0u;
    __syncthreads();
    if (lastFlag) {
        __threadfence();                   // acquire: invalidate caches before reads
        const int y0 = y[0];
        double ls = 0.0, rs = 0.0;
        for (int i = t; i < N; i += 256) {
            ls += (double)lossrow[i];
            if (i > 0 && y[i] == y0 && cnt[i] <= 1u) {
                float d2 = 0.f;
                for (int c = 0; c < C; ++c) {
                    float d = Y[(size_t)i * C + c] - Y[c];
                    d2 += d * d;
                }
                rs += (double)sqrtf(fmaxf(d2, 0.f));
            }
        }
        for (int o = 32; o; o >>= 1) {
            ls += __shfl_down(ls, o);
            rs += __shfl_down(rs, o);
        }
        __shared__ double dl[4], dr[4];
        if ((t & 63) == 0) { dl[t >> 6] = ls; dr[t >> 6] = rs; }
        __syncthreads();
        if (t == 0) {
            double L = (dl[0] + dl[1] + dl[2] + dl[3]) / (double)N;
            double R = (dr[0] + dr[1] + dr[2] + dr[3]);
            out[0] = (float)(L + (double)ALPHA * R);
        }
    }
}

// ---------------------------------------------------------------------------
extern "C" void kernel_launch(void* const* d_in, const int* in_sizes, int n_in,
                              void* d_out, int out_size, void* d_ws, size_t ws_size,
                              hipStream_t stream) {
    const float* x  = (const float*)d_in[0];   // (N, D)
    const int*   y  = (const int*)d_in[1];     // (N,)
    const float* Y  = (const float*)d_in[2];   // (N, C)
    const float* W  = (const float*)d_in[3];   // (D, C)
    const float* b  = (const float*)d_in[4];   // (C,)
    float* out = (float*)d_out;

    float* wsf      = (float*)d_ws;
    float* lossrow  = wsf;                       // N f32
    float* sq       = wsf + N;                   // N f32
    float* dot0     = wsf + 2 * N;               // N f32
    unsigned* cnt   = (unsigned*)(wsf + 3 * N);  // N u32
    __bf16* xb      = (__bf16*)(wsf + 4 * N);    // N*D bf16 (4 MB)
    __bf16* Wtb     = (__bf16*)((char*)xb + (size_t)N * D * 2); // C*D bf16
    unsigned* done  = (unsigned*)((char*)Wtb + (size_t)C * D * 2);

    prep_kernel<<<N + (D * C) / 256, 256, 0, stream>>>(x, sq, dot0, xb, W, Wtb, cnt, done);
    fused_mfma<<<NBLK, 256, 0, stream>>>(xb, Wtb, sq, dot0, y, b, cnt, lossrow, Y, done, out);
}

// Round 5
// 115.527 us; speedup vs baseline: 1.2463x; 1.2463x over previous
//
#include <hip/hip_runtime.h>
#include <math.h>
#include <stdint.h>

#define N 4096
#define D 512
#define C 128
#define ALPHA 0.0005f
#define NT_TILES 32                 // N/128
#define TRI (NT_TILES * (NT_TILES + 1) / 2)   // 528 count tiles
#define NBLK (TRI + N / 128)                  // + 32 CE tiles = 560

typedef __bf16 bf16x8 __attribute__((ext_vector_type(8)));
typedef float f32x4 __attribute__((ext_vector_type(4)));

// async global->LDS, 16B per lane. LDS dest must be wave-uniform base + lane*16.
__device__ __forceinline__ void async16(const void* g, void* l) {
    __builtin_amdgcn_global_load_lds(
        reinterpret_cast<const __attribute__((address_space(1))) uint32_t*>(
            reinterpret_cast<uintptr_t>(g)),
        reinterpret_cast<__attribute__((address_space(3))) uint32_t*>(
            reinterpret_cast<uintptr_t>(l)),
        16, 0, 0);
}

// ---------------------------------------------------------------------------
// prep: blocks [0,N)    : sq[i]=||x_i||^2 ; dot0[i]=x_i.x_0 ; xb=bf16(x); cnt[i]=0
//       blocks [N,N+256): Wtb[n][k] = bf16(W[k][n])
// ---------------------------------------------------------------------------
__global__ __launch_bounds__(256) void prep_kernel(const float* __restrict__ x,
                                                   float* __restrict__ sq,
                                                   float* __restrict__ dot0,
                                                   __bf16* __restrict__ xb,
                                                   const float* __restrict__ W,
                                                   __bf16* __restrict__ Wtb,
                                                   unsigned* __restrict__ cnt) {
    if (blockIdx.x >= N) {
        const int tid = (blockIdx.x - N) * 256 + threadIdx.x;  // 0..D*C-1
        const int k = tid >> 7;
        const int n = tid & 127;
        Wtb[(size_t)n * D + k] = (__bf16)W[tid];
        return;
    }
    const int i = blockIdx.x;
    const int t = threadIdx.x;
    if (t == 0) cnt[i] = 0u;
    float s1 = 0.f, s2 = 0.f;
    for (int k = t; k < D; k += 256) {
        float v = x[(size_t)i * D + k];
        xb[(size_t)i * D + k] = (__bf16)v;
        s1 += v * v;
        s2 += v * x[k];           // x[0,k]
    }
    for (int o = 32; o; o >>= 1) {
        s1 += __shfl_down(s1, o);
        s2 += __shfl_down(s2, o);
    }
    __shared__ float r1[4], r2[4];
    if ((t & 63) == 0) { r1[t >> 6] = s1; r2[t >> 6] = s2; }
    __syncthreads();
    if (t == 0) {
        sq[i]   = r1[0] + r1[1] + r1[2] + r1[3];
        dot0[i] = r2[0] + r2[1] + r2[2] + r2[3];
    }
}

// ---------------------------------------------------------------------------
// fused_mfma:
//   blocks [0,TRI)      : neighbor-count tile (ti,tj), tj>=ti, symmetric update
//   blocks [TRI,TRI+32) : CE tile (128 rows x 128 logits + log-softmax)
// 128x128 tile, BK=32, ping-pong double-buffered async staging (ONE barrier
// per K-iter; prefetch k+1 is in flight during compute k). 4 waves 2x2,
// 4x4 frags of mfma_f32_16x16x32_bf16.
// LDS slot swizzle slot = c ^ (r&3) ^ ((r>>2)&3): global loads stay
// coalesced (per-row permutation of one 64B segment), frag ds_read_b128
// lands at <=2-way bank aliasing (free).
// ---------------------------------------------------------------------------
__global__ __launch_bounds__(256) void fused_mfma(const __bf16* __restrict__ xb,
                                                  const __bf16* __restrict__ Wtb,
                                                  const float* __restrict__ sq,
                                                  const float* __restrict__ dot0,
                                                  const int* __restrict__ y,
                                                  const float* __restrict__ b,
                                                  unsigned* __restrict__ cnt,
                                                  float* __restrict__ lossrow) {
    __shared__ __bf16 Alds[2][128 * 32];
    __shared__ __bf16 Blds[2][128 * 32];
    __shared__ float rmax[128][2];
    __shared__ float rsum[128][2];
    const int t = threadIdx.x;
    const int w = t >> 6, l = t & 63;
    const int wy = w >> 1, wx = w & 1;
    const int kg = l >> 4, lr = l & 15;

    const int bid = (int)blockIdx.x;
    const bool isCE = (bid >= TRI);
    int bi, bj;
    bool diag = false;
    const __bf16* Bbase;
    if (isCE) {
        bi = (bid - TRI) * 128;
        bj = 0;
        Bbase = Wtb;
    } else {
        int tj = (int)((sqrtf(8.f * (float)bid + 1.f) - 1.f) * 0.5f);
        while (tj * (tj + 1) / 2 > bid) --tj;
        while ((tj + 1) * (tj + 2) / 2 <= bid) ++tj;
        const int ti = bid - tj * (tj + 1) / 2;
        bi = ti * 128;
        bj = tj * 128;
        diag = (ti == tj);
        Bbase = xb + (size_t)bj * D;
    }
    const __bf16* Abase = xb + (size_t)bi * D;

    f32x4 acc[4][4];
    const f32x4 zero = {0.f, 0.f, 0.f, 0.f};
#pragma unroll
    for (int mt = 0; mt < 4; ++mt)
#pragma unroll
        for (int nt = 0; nt < 4; ++nt) acc[mt][nt] = zero;

    // staging: 512 x 16B per matrix per tile; 2 per thread. slot-swizzled src.
    const int e0 = t, e1 = t + 256;
    const int r0 = e0 >> 2, c0 = e0 & 3;
    const int r1 = e1 >> 2, c1 = e1 & 3;
    const int sc0 = (c0 ^ (r0 & 3) ^ ((r0 >> 2) & 3)) & 3;
    const int sc1 = (c1 ^ (r1 & 3) ^ ((r1 >> 2) & 3)) & 3;

    // prologue: stage tile 0 into buffer 0
    {
        async16(Abase + (size_t)r0 * D + 0 + sc0 * 8, (char*)Alds[0] + e0 * 16);
        async16(Abase + (size_t)r1 * D + 0 + sc1 * 8, (char*)Alds[0] + e1 * 16);
        if (!diag) {
            async16(Bbase + (size_t)r0 * D + 0 + sc0 * 8, (char*)Blds[0] + e0 * 16);
            async16(Bbase + (size_t)r1 * D + 0 + sc1 * 8, (char*)Blds[0] + e1 * 16);
        }
    }

    int pb = 0;
    for (int kc = 0; kc < D; kc += 32, pb ^= 1) {
        __syncthreads();   // drains prefetch for tile kc; fences buffer reuse
        if (kc + 32 < D) {
            const int nb = pb ^ 1;
            async16(Abase + (size_t)r0 * D + (kc + 32) + sc0 * 8, (char*)Alds[nb] + e0 * 16);
            async16(Abase + (size_t)r1 * D + (kc + 32) + sc1 * 8, (char*)Alds[nb] + e1 * 16);
            if (!diag) {
                async16(Bbase + (size_t)r0 * D + (kc + 32) + sc0 * 8, (char*)Blds[nb] + e0 * 16);
                async16(Bbase + (size_t)r1 * D + (kc + 32) + sc1 * 8, (char*)Blds[nb] + e1 * 16);
            }
        }
        const __bf16* Al = Alds[pb];
        const __bf16* Bl = diag ? Alds[pb] : Blds[pb];
        bf16x8 av[4], bv[4];
#pragma unroll
        for (int mt = 0; mt < 4; ++mt) {
            const int row = wy * 64 + mt * 16 + lr;
            const int slot = (kg ^ (row & 3) ^ ((row >> 2) & 3)) & 3;
            av[mt] = *(const bf16x8*)(Al + row * 32 + slot * 8);
        }
#pragma unroll
        for (int nt = 0; nt < 4; ++nt) {
            const int row = wx * 64 + nt * 16 + lr;
            const int slot = (kg ^ (row & 3) ^ ((row >> 2) & 3)) & 3;
            bv[nt] = *(const bf16x8*)(Bl + row * 32 + slot * 8);
        }
#pragma unroll
        for (int mt = 0; mt < 4; ++mt)
#pragma unroll
            for (int nt = 0; nt < 4; ++nt)
                acc[mt][nt] = __builtin_amdgcn_mfma_f32_16x16x32_bf16(av[mt], bv[nt], acc[mt][nt], 0, 0, 0);
    }

    if (isCE) {
        // ---- CE epilogue: log-softmax over 128 cols, pick col y[i] ----
        int jn[4]; float bb[4];
#pragma unroll
        for (int nt = 0; nt < 4; ++nt) { jn[nt] = wx * 64 + nt * 16 + lr; bb[nt] = b[jn[nt]]; }
#pragma unroll
        for (int mt = 0; mt < 4; ++mt)
#pragma unroll
            for (int r = 0; r < 4; ++r) {
                float m = acc[mt][0][r] + bb[0];
#pragma unroll
                for (int nt = 1; nt < 4; ++nt) m = fmaxf(m, acc[mt][nt][r] + bb[nt]);
                m = fmaxf(m, __shfl_xor(m, 1));
                m = fmaxf(m, __shfl_xor(m, 2));
                m = fmaxf(m, __shfl_xor(m, 4));
                m = fmaxf(m, __shfl_xor(m, 8));
                if (lr == 0) rmax[wy * 64 + mt * 16 + kg * 4 + r][wx] = m;
            }
        __syncthreads();
        float mrow[4][4];
#pragma unroll
        for (int mt = 0; mt < 4; ++mt)
#pragma unroll
            for (int r = 0; r < 4; ++r) {
                const int ri = wy * 64 + mt * 16 + kg * 4 + r;
                mrow[mt][r] = fmaxf(rmax[ri][0], rmax[ri][1]);
                float s = 0.f;
#pragma unroll
                for (int nt = 0; nt < 4; ++nt) s += expf(acc[mt][nt][r] + bb[nt] - mrow[mt][r]);
                s += __shfl_xor(s, 1);
                s += __shfl_xor(s, 2);
                s += __shfl_xor(s, 4);
                s += __shfl_xor(s, 8);
                if (lr == 0) rsum[ri][wx] = s;
            }
        __syncthreads();
#pragma unroll
        for (int mt = 0; mt < 4; ++mt)
#pragma unroll
            for (int r = 0; r < 4; ++r) {
                const int ri = wy * 64 + mt * 16 + kg * 4 + r;
                const int i = bi + ri;
                const float s = rsum[ri][0] + rsum[ri][1];
                const int yi = y[i];
#pragma unroll
                for (int nt = 0; nt < 4; ++nt)
                    if (jn[nt] == yi)
                        lossrow[i] = -(acc[mt][nt][r] + bb[nt] - mrow[mt][r] - logf(s));
            }
    } else {
        // ---- count epilogue (symmetric) ----
        const float sq0 = sq[0];
        int jn[4]; float sqj[4], thrj[4];
#pragma unroll
        for (int nt = 0; nt < 4; ++nt) {
            jn[nt] = bj + wx * 64 + nt * 16 + lr;
            sqj[nt] = sq[jn[nt]];
            thrj[nt] = sq0 - 2.0f * dot0[jn[nt]];
        }
        unsigned cj[4] = {0u, 0u, 0u, 0u};
#pragma unroll
        for (int mt = 0; mt < 4; ++mt)
#pragma unroll
            for (int r = 0; r < 4; ++r) {
                const int i = bi + wy * 64 + mt * 16 + kg * 4 + r;
                const float thri = sq0 - 2.0f * dot0[i];
                const float sqi = sq[i];
                unsigned ci = 0;
                if (diag) {
#pragma unroll
                    for (int nt = 0; nt < 4; ++nt) {
                        const float d = acc[mt][nt][r];
                        const int j = jn[nt];
                        if (sqj[nt] - 2.0f * d < thri && j != i && j != 0) ++ci;
                    }
                } else {
                    // bj > bi: j >= 128 > 0 and i < bj <= j, no guards needed
#pragma unroll
                    for (int nt = 0; nt < 4; ++nt) {
                        const float d = acc[mt][nt][r];
                        if (sqj[nt] - 2.0f * d < thri) ++ci;
                        if (sqi - 2.0f * d < thrj[nt] && i != 0) ++cj[nt];
                    }
                }
                ci += __shfl_xor((int)ci, 1);
                ci += __shfl_xor((int)ci, 2);
                ci += __shfl_xor((int)ci, 4);
                ci += __shfl_xor((int)ci, 8);
                if (lr == 0 && ci) atomicAdd(&cnt[i], ci);
            }
        if (!diag) {
#pragma unroll
            for (int nt = 0; nt < 4; ++nt) {
                unsigned v = cj[nt];
                v += __shfl_xor((int)v, 16);
                v += __shfl_xor((int)v, 32);
                if (l < 16 && v) atomicAdd(&cnt[jn[nt]], v);
            }
        }
    }
}

// ---------------------------------------------------------------------------
// finalize: out = mean(lossrow) + ALPHA * sum_{i>0, y_i==y_0, cnt[i]<=1} ||Y_i - Y_0||
// ---------------------------------------------------------------------------
__global__ __launch_bounds__(256) void final_kernel(const float* __restrict__ lossrow,
                                                    const unsigned* __restrict__ cnt,
                                                    const int* __restrict__ y,
                                                    const float* __restrict__ Y,
                                                    float* __restrict__ out) {
    const int t = threadIdx.x;
    const int y0 = y[0];
    double ls = 0.0, rs = 0.0;
    for (int i = t; i < N; i += 256) {
        ls += (double)lossrow[i];
        if (i > 0 && y[i] == y0 && cnt[i] <= 1u) {
            float d2 = 0.f;
            for (int c = 0; c < C; ++c) {
                float d = Y[(size_t)i * C + c] - Y[c];
                d2 += d * d;
            }
            rs += (double)sqrtf(fmaxf(d2, 0.f));
        }
    }
    for (int o = 32; o; o >>= 1) {
        ls += __shfl_down(ls, o);
        rs += __shfl_down(rs, o);
    }
    __shared__ double dl[4], dr[4];
    if ((t & 63) == 0) { dl[t >> 6] = ls; dr[t >> 6] = rs; }
    __syncthreads();
    if (t == 0) {
        double L = (dl[0] + dl[1] + dl[2] + dl[3]) / (double)N;
        double R = (dr[0] + dr[1] + dr[2] + dr[3]);
        out[0] = (float)(L + (double)ALPHA * R);
    }
}

// ---------------------------------------------------------------------------
extern "C" void kernel_launch(void* const* d_in, const int* in_sizes, int n_in,
                              void* d_out, int out_size, void* d_ws, size_t ws_size,
                              hipStream_t stream) {
    const float* x  = (const float*)d_in[0];   // (N, D)
    const int*   y  = (const int*)d_in[1];     // (N,)
    const float* Y  = (const float*)d_in[2];   // (N, C)
    const float* W  = (const float*)d_in[3];   // (D, C)
    const float* b  = (const float*)d_in[4];   // (C,)
    float* out = (float*)d_out;

    float* wsf      = (float*)d_ws;
    float* lossrow  = wsf;                       // N f32
    float* sq       = wsf + N;                   // N f32
    float* dot0     = wsf + 2 * N;               // N f32
    unsigned* cnt   = (unsigned*)(wsf + 3 * N);  // N u32
    __bf16* xb      = (__bf16*)(wsf + 4 * N);    // N*D bf16 (4 MB)
    __bf16* Wtb     = (__bf16*)((char*)xb + (size_t)N * D * 2); // C*D bf16

    prep_kernel<<<N + (D * C) / 256, 256, 0, stream>>>(x, sq, dot0, xb, W, Wtb, cnt);
    fused_mfma<<<NBLK, 256, 0, stream>>>(xb, Wtb, sq, dot0, y, b, cnt, lossrow);
    final_kernel<<<1, 256, 0, stream>>>(lossrow, cnt, y, Y, out);
}